// Round 5
// baseline (415.648 us; speedup 1.0000x reference)
//
#include <hip/hip_runtime.h>

#define NROWS 4
#define NBLK  2048            // NBLK * NROWS = 8192 batch rows
#define C1f 0.92387953251128674f
#define S1f 0.38268343236508978f
#define R2f 0.70710678118654752f
#define TWO_PI 6.28318530717958648f

// +2 complex every 64: keeps 16B alignment for b128, breaks pow2 strides
#define CIDX(c) ((c) + (((c) >> 6) << 1))

typedef float2 cf;

__device__ __forceinline__ cf cadd(cf a, cf b){ return make_float2(a.x+b.x, a.y+b.y); }
__device__ __forceinline__ cf csub(cf a, cf b){ return make_float2(a.x-b.x, a.y-b.y); }
__device__ __forceinline__ cf cmul(cf a, cf b){ return make_float2(a.x*b.x - a.y*b.y, a.x*b.y + a.y*b.x); }
__device__ __forceinline__ cf cmulNI(cf a){ return make_float2(a.y, -a.x); }
__device__ __forceinline__ cf cW1(cf a){ return make_float2(C1f*a.x + S1f*a.y, C1f*a.y - S1f*a.x); }
__device__ __forceinline__ cf cW2(cf a){ return make_float2(R2f*(a.x + a.y), R2f*(a.y - a.x)); }
__device__ __forceinline__ cf cW3(cf a){ return make_float2(S1f*a.x + C1f*a.y, S1f*a.y - C1f*a.x); }
__device__ __forceinline__ cf cW6(cf a){ return make_float2(R2f*(a.y - a.x), -R2f*(a.x + a.y)); }
__device__ __forceinline__ cf cNW1(cf a){ return make_float2(-(C1f*a.x + S1f*a.y), S1f*a.x - C1f*a.y); }

// in-register 16-point DFT (natural in/out), radix-4 DIF
__device__ __forceinline__ void fft16(cf v[16]) {
    cf y[16];
    #pragma unroll
    for (int j1 = 0; j1 < 4; ++j1) {
        cf a0 = v[j1], a1 = v[j1+4], a2 = v[j1+8], a3 = v[j1+12];
        cf s0 = cadd(a0,a2), d0 = csub(a0,a2);
        cf s1 = cadd(a1,a3), d1 = csub(a1,a3);
        cf b0 = cadd(s0,s1);
        cf b1 = make_float2(d0.x + d1.y, d0.y - d1.x);
        cf b2 = csub(s0,s1);
        cf b3 = make_float2(d0.x - d1.y, d0.y + d1.x);
        if (j1 == 0)      { y[0]=b0; y[4]=b1;      y[8]=b2;          y[12]=b3; }
        else if (j1 == 1) { y[1]=b0; y[5]=cW1(b1); y[9]=cW2(b2);     y[13]=cW3(b3); }
        else if (j1 == 2) { y[2]=b0; y[6]=cW2(b1); y[10]=cmulNI(b2); y[14]=cW6(b3); }
        else              { y[3]=b0; y[7]=cW3(b1); y[11]=cW6(b2);    y[15]=cNW1(b3); }
    }
    #pragma unroll
    for (int p1 = 0; p1 < 4; ++p1) {
        cf c0 = y[4*p1], c1v = y[4*p1+1], c2v = y[4*p1+2], c3v = y[4*p1+3];
        cf s0 = cadd(c0,c2v), d0 = csub(c0,c2v);
        cf s1 = cadd(c1v,c3v), d1 = csub(c1v,c3v);
        v[p1]    = cadd(s0,s1);
        v[4+p1]  = make_float2(d0.x + d1.y, d0.y - d1.x);
        v[8+p1]  = csub(s0,s1);
        v[12+p1] = make_float2(d0.x - d1.y, d0.y + d1.x);
    }
}

// 64-lane sum via DPP; valid in lane 63
__device__ __forceinline__ float wred(float x) {
    x += __int_as_float(__builtin_amdgcn_update_dpp(0, __float_as_int(x), 0x111, 0xf, 0xf, false));
    x += __int_as_float(__builtin_amdgcn_update_dpp(0, __float_as_int(x), 0x112, 0xf, 0xf, false));
    x += __int_as_float(__builtin_amdgcn_update_dpp(0, __float_as_int(x), 0x114, 0xf, 0xf, false));
    x += __int_as_float(__builtin_amdgcn_update_dpp(0, __float_as_int(x), 0x118, 0xf, 0xf, false));
    x += __int_as_float(__builtin_amdgcn_update_dpp(0, __float_as_int(x), 0x142, 0xa, 0xf, false));
    x += __int_as_float(__builtin_amdgcn_update_dpp(0, __float_as_int(x), 0x143, 0xc, 0xf, false));
    return x;
}

// LDS-only barrier: register prefetch loads stay in flight (vmcnt untouched)
__device__ __forceinline__ void bar_lds() {
    asm volatile("s_waitcnt lgkmcnt(0)" ::: "memory");
    __builtin_amdgcn_s_barrier();
}

__global__ __launch_bounds__(256, 4)
void fftmlp_r16ip(const float* __restrict__ x, const float* __restrict__ w1,
                  const float* __restrict__ w2, float* __restrict__ out) {
    __shared__ __align__(16) cf buf[CIDX(4095) + 1];   // single in-place work buffer
    __shared__ float sred[40];
    const int t  = threadIdx.x;
    const int b0 = blockIdx.x * NROWS;
    const cf* __restrict__ w1c = (const cf*)w1;
    const cf* __restrict__ w2c = (const cf*)w2;
    const cf* __restrict__ xc  = (const cf*)x;

    // ---- prefetch row 0 into registers; prologue computes while loads fly ----
    cf P[16];
    {
        const cf* __restrict__ xr = xc + (size_t)b0 * 4096;
        #pragma unroll
        for (int q = 0; q < 16; ++q) P[q] = xr[t + 256*q];
    }

    float sn, cs;
    __sincosf(-TWO_PI * (float)t * (1.0f/4096.0f), &sn, &cs);
    const cf wA = make_float2(cs, sn);
    __sincosf(-TWO_PI * (float)(t & 15) * (1.0f/256.0f), &sn, &cs);
    const cf wB = make_float2(cs, sn);
    const int c0i = ((t & 15) << 4) | (t >> 4);
    __sincosf(-TWO_PI * (float)c0i * (1.0f/1024.0f), &sn, &cs);
    const cf wk = make_float2(cs, sn);
    const cf r1 = wk;
    const cf r2 = cmul(r1, wk);
    const cf r3 = cmul(r2, wk);
    const cf r4 = cmul(r3, wk);
    const cf w2v0 = w2c[c0i], w2v1 = w2c[256 + c0i], w2v2 = w2c[512 + c0i], w2v3 = w2c[768 + c0i];

    for (int rr = 0; rr < NROWS; ++rr) {
        // ---- pass A: consume P (x row) x w1, fft16, twiddle, scatter to buf ----
        {
            cf v[16];
            #pragma unroll
            for (int q = 0; q < 16; ++q)
                v[q] = cmul(P[q], w1c[t + 256*q]);
            fft16(v);
            buf[CIDX(t)] = v[0];
            cf tw = wA;
            #pragma unroll
            for (int p = 1; p < 16; ++p) {
                buf[CIDX(p*256 + t)] = cmul(v[p], tw);
                tw = cmul(tw, wA);
            }
        }
        bar_lds();

        // ---- issue next row's prefetch here (low register pressure point);
        //      loads stay in flight across pass B + final ----
        if (rr + 1 < NROWS) {
            const cf* __restrict__ xn = xc + (size_t)(b0 + rr + 1) * 4096;
            #pragma unroll
            for (int q = 0; q < 16; ++q) P[q] = xn[t + 256*q];
        }

        // ---- pass B: in-place (each thread reads/writes its own 16 slots) ----
        {
            const int p    = t >> 4;
            const int jp   = t & 15;
            const int base = p*256 + jp;
            cf u[16];
            #pragma unroll
            for (int q = 0; q < 16; ++q) u[q] = buf[CIDX(base + 16*q)];
            fft16(u);
            buf[CIDX(base)] = u[0];
            cf tw = wB;
            #pragma unroll
            for (int pp = 1; pp < 16; ++pp) {
                buf[CIDX(base + 16*pp)] = cmul(u[pp], tw);
                tw = cmul(tw, wB);
            }
        }
        bar_lds();

        // ---- final: 4 needed bins of 16-pt DFT + ReLU + w2 + 5-bin layer-2 DFT ----
        cf acc0, acc1, acc2, acc3, acc4;
        {
            cf z[16];
            const float4* __restrict__ lp = reinterpret_cast<const float4*>(&buf[CIDX(16*t)]);
            #pragma unroll
            for (int j2 = 0; j2 < 8; ++j2) {
                float4 zv = lp[j2];
                z[2*j2]   = make_float2(zv.x, zv.y);
                z[2*j2+1] = make_float2(zv.z, zv.w);
            }
            cf A[4][4];
            #pragma unroll
            for (int bb = 0; bb < 4; ++bb) {
                cf a0 = z[bb], a1 = z[bb+4], a2 = z[bb+8], a3 = z[bb+12];
                cf s0 = cadd(a0,a2), d0 = csub(a0,a2);
                cf s1 = cadd(a1,a3), d1 = csub(a1,a3);
                A[bb][0] = cadd(s0,s1);
                A[bb][1] = make_float2(d0.x + d1.y, d0.y - d1.x);
                A[bb][2] = csub(s0,s1);
                A[bb][3] = make_float2(d0.x - d1.y, d0.y + d1.x);
            }
            cf F0 = cadd(cadd(A[0][0], A[1][0]),      cadd(A[2][0],      A[3][0]));
            cf F1 = cadd(cadd(A[0][1], cW1(A[1][1])), cadd(cW2(A[2][1]), cW3(A[3][1])));
            cf F2 = cadd(cadd(A[0][2], cW2(A[1][2])), cadd(cmulNI(A[2][2]), cW6(A[3][2])));
            cf F3 = cadd(cadd(A[0][3], cW3(A[1][3])), cadd(cW6(A[2][3]), cNW1(A[3][3])));

            cf h, P0, P1, P2, P3;
            h = make_float2(fmaxf(F0.x,0.f), fmaxf(F0.y,0.f)); P0 = cmul(h, w2v0);
            h = make_float2(fmaxf(F1.x,0.f), fmaxf(F1.y,0.f)); P1 = cmul(h, w2v1);
            h = make_float2(fmaxf(F2.x,0.f), fmaxf(F2.y,0.f)); P2 = cmul(h, w2v2);
            h = make_float2(fmaxf(F3.x,0.f), fmaxf(F3.y,0.f)); P3 = cmul(h, w2v3);

            cf s0 = cadd(P0,P2), d0 = csub(P0,P2);
            cf s1 = cadd(P1,P3), d1 = csub(P1,P3);
            cf G0 = cadd(s0,s1);
            cf G1 = make_float2(d0.x + d1.y, d0.y - d1.x);
            cf G2 = csub(s0,s1);
            cf G3 = make_float2(d0.x - d1.y, d0.y + d1.x);
            acc0 = G0;
            acc1 = cmul(G1, r1);
            acc2 = cmul(G2, r2);
            acc3 = cmul(G3, r3);
            acc4 = cmul(G0, r4);
        }

        // ---- reduce 256 threads -> 10 floats, store row ----
        float rv[10] = {acc0.x, acc0.y, acc1.x, acc1.y, acc2.x,
                        acc2.y, acc3.x, acc3.y, acc4.x, acc4.y};
        #pragma unroll
        for (int i = 0; i < 10; ++i) rv[i] = wred(rv[i]);
        const int lane = t & 63, wv = t >> 6;
        if (lane == 63) {
            #pragma unroll
            for (int i = 0; i < 10; ++i) sred[wv*10 + i] = rv[i];
        }
        bar_lds();   // sred visible; also: all final buf-reads done -> next pass A may write
        if (t < 10) {
            out[(b0 + rr)*10 + t] = sred[t] + sred[10+t] + sred[20+t] + sred[30+t];
        }
    }
}

extern "C" void kernel_launch(void* const* d_in, const int* in_sizes, int n_in,
                              void* d_out, int out_size, void* d_ws, size_t ws_size,
                              hipStream_t stream) {
    const float* x  = (const float*)d_in[0];
    const float* w1 = (const float*)d_in[1];
    const float* w2 = (const float*)d_in[2];
    float* out = (float*)d_out;
    fftmlp_r16ip<<<NBLK, 256, 0, stream>>>(x, w1, w2, out);
}

// Round 6
// 391.910 us; speedup vs baseline: 1.0606x; 1.0606x over previous
//
#include <hip/hip_runtime.h>

#define NROWS 4
#define NBLK  2048            // NBLK * NROWS = 8192 batch rows
#define C1f 0.92387953251128674f
#define S1f 0.38268343236508978f
#define R2f 0.70710678118654752f
#define TWO_PI 6.28318530717958648f

// +2 complex every 64: keeps 16B alignment for b128, breaks pow2 strides
#define CIDX(c) ((c) + (((c) >> 6) << 1))

typedef float2 cf;

__device__ __forceinline__ cf cadd(cf a, cf b){ return make_float2(a.x+b.x, a.y+b.y); }
__device__ __forceinline__ cf csub(cf a, cf b){ return make_float2(a.x-b.x, a.y-b.y); }
__device__ __forceinline__ cf cmul(cf a, cf b){ return make_float2(a.x*b.x - a.y*b.y, a.x*b.y + a.y*b.x); }
__device__ __forceinline__ cf cmulNI(cf a){ return make_float2(a.y, -a.x); }
__device__ __forceinline__ cf cW1(cf a){ return make_float2(C1f*a.x + S1f*a.y, C1f*a.y - S1f*a.x); }
__device__ __forceinline__ cf cW2(cf a){ return make_float2(R2f*(a.x + a.y), R2f*(a.y - a.x)); }
__device__ __forceinline__ cf cW3(cf a){ return make_float2(S1f*a.x + C1f*a.y, S1f*a.y - C1f*a.x); }
__device__ __forceinline__ cf cW6(cf a){ return make_float2(R2f*(a.y - a.x), -R2f*(a.x + a.y)); }
__device__ __forceinline__ cf cNW1(cf a){ return make_float2(-(C1f*a.x + S1f*a.y), S1f*a.x - C1f*a.y); }

// in-register 16-point DFT (natural in/out), radix-4 DIF
__device__ __forceinline__ void fft16(cf v[16]) {
    cf y[16];
    #pragma unroll
    for (int j1 = 0; j1 < 4; ++j1) {
        cf a0 = v[j1], a1 = v[j1+4], a2 = v[j1+8], a3 = v[j1+12];
        cf s0 = cadd(a0,a2), d0 = csub(a0,a2);
        cf s1 = cadd(a1,a3), d1 = csub(a1,a3);
        cf b0 = cadd(s0,s1);
        cf b1 = make_float2(d0.x + d1.y, d0.y - d1.x);
        cf b2 = csub(s0,s1);
        cf b3 = make_float2(d0.x - d1.y, d0.y + d1.x);
        if (j1 == 0)      { y[0]=b0; y[4]=b1;      y[8]=b2;          y[12]=b3; }
        else if (j1 == 1) { y[1]=b0; y[5]=cW1(b1); y[9]=cW2(b2);     y[13]=cW3(b3); }
        else if (j1 == 2) { y[2]=b0; y[6]=cW2(b1); y[10]=cmulNI(b2); y[14]=cW6(b3); }
        else              { y[3]=b0; y[7]=cW3(b1); y[11]=cW6(b2);    y[15]=cNW1(b3); }
    }
    #pragma unroll
    for (int p1 = 0; p1 < 4; ++p1) {
        cf c0 = y[4*p1], c1v = y[4*p1+1], c2v = y[4*p1+2], c3v = y[4*p1+3];
        cf s0 = cadd(c0,c2v), d0 = csub(c0,c2v);
        cf s1 = cadd(c1v,c3v), d1 = csub(c1v,c3v);
        v[p1]    = cadd(s0,s1);
        v[4+p1]  = make_float2(d0.x + d1.y, d0.y - d1.x);
        v[8+p1]  = csub(s0,s1);
        v[12+p1] = make_float2(d0.x - d1.y, d0.y + d1.x);
    }
}

// 64-lane sum via DPP; valid in lane 63
__device__ __forceinline__ float wred(float x) {
    x += __int_as_float(__builtin_amdgcn_update_dpp(0, __float_as_int(x), 0x111, 0xf, 0xf, false));
    x += __int_as_float(__builtin_amdgcn_update_dpp(0, __float_as_int(x), 0x112, 0xf, 0xf, false));
    x += __int_as_float(__builtin_amdgcn_update_dpp(0, __float_as_int(x), 0x114, 0xf, 0xf, false));
    x += __int_as_float(__builtin_amdgcn_update_dpp(0, __float_as_int(x), 0x118, 0xf, 0xf, false));
    x += __int_as_float(__builtin_amdgcn_update_dpp(0, __float_as_int(x), 0x142, 0xa, 0xf, false));
    x += __int_as_float(__builtin_amdgcn_update_dpp(0, __float_as_int(x), 0x143, 0xc, 0xf, false));
    return x;
}

// LDS-only barrier: register prefetch loads stay in flight (vmcnt untouched)
__device__ __forceinline__ void bar_lds() {
    asm volatile("s_waitcnt lgkmcnt(0)" ::: "memory");
    __builtin_amdgcn_s_barrier();
}

__global__ void __launch_bounds__(256)
__attribute__((amdgpu_waves_per_eu(4, 4)))
fftmlp_r16ip(const float* __restrict__ x, const float* __restrict__ w1,
             const float* __restrict__ w2, float* __restrict__ out) {
    __shared__ __align__(16) cf buf[CIDX(4095) + 1];   // single in-place work buffer
    __shared__ float sred[40];
    const int t  = threadIdx.x;
    const int b0 = blockIdx.x * NROWS;
    const cf* __restrict__ w1c = (const cf*)w1;
    const cf* __restrict__ w2c = (const cf*)w2;
    const cf* __restrict__ xc  = (const cf*)x;

    // ---- prefetch row 0 into registers; prologue computes while loads fly ----
    cf P[16];
    {
        const cf* __restrict__ xr = xc + (size_t)b0 * 4096;
        #pragma unroll
        for (int q = 0; q < 16; ++q) P[q] = xr[t + 256*q];
    }

    float sn, cs;
    __sincosf(-TWO_PI * (float)t * (1.0f/4096.0f), &sn, &cs);
    const cf wA = make_float2(cs, sn);
    __sincosf(-TWO_PI * (float)(t & 15) * (1.0f/256.0f), &sn, &cs);
    const cf wB = make_float2(cs, sn);
    const int c0i = ((t & 15) << 4) | (t >> 4);
    __sincosf(-TWO_PI * (float)c0i * (1.0f/1024.0f), &sn, &cs);
    const cf wk = make_float2(cs, sn);
    const cf r1 = wk;
    const cf r2 = cmul(r1, wk);
    const cf r3 = cmul(r2, wk);
    const cf r4 = cmul(r3, wk);
    const cf w2v0 = w2c[c0i], w2v1 = w2c[256 + c0i], w2v2 = w2c[512 + c0i], w2v3 = w2c[768 + c0i];

    for (int rr = 0; rr < NROWS; ++rr) {
        // ---- pass A: consume P (x row) x w1, fft16, twiddle, scatter to buf ----
        {
            cf v[16];
            #pragma unroll
            for (int q = 0; q < 16; ++q)
                v[q] = cmul(P[q], w1c[t + 256*q]);
            fft16(v);
            buf[CIDX(t)] = v[0];
            cf tw = wA;
            #pragma unroll
            for (int p = 1; p < 16; ++p) {
                buf[CIDX(p*256 + t)] = cmul(v[p], tw);
                tw = cmul(tw, wA);
            }
        }
        bar_lds();

        // ---- issue next row's prefetch (low register pressure point);
        //      loads stay in flight across pass B + final ----
        if (rr + 1 < NROWS) {
            const cf* __restrict__ xn = xc + (size_t)(b0 + rr + 1) * 4096;
            #pragma unroll
            for (int q = 0; q < 16; ++q) P[q] = xn[t + 256*q];
        }

        // ---- pass B: in-place (each thread reads/writes its own 16 slots) ----
        {
            const int p    = t >> 4;
            const int jp   = t & 15;
            const int base = p*256 + jp;
            cf u[16];
            #pragma unroll
            for (int q = 0; q < 16; ++q) u[q] = buf[CIDX(base + 16*q)];
            fft16(u);
            buf[CIDX(base)] = u[0];
            cf tw = wB;
            #pragma unroll
            for (int pp = 1; pp < 16; ++pp) {
                buf[CIDX(base + 16*pp)] = cmul(u[pp], tw);
                tw = cmul(tw, wB);
            }
        }
        bar_lds();

        // ---- final: 4 needed bins of 16-pt DFT + ReLU + w2 + 5-bin layer-2 DFT ----
        cf acc0, acc1, acc2, acc3, acc4;
        {
            cf z[16];
            const float4* __restrict__ lp = reinterpret_cast<const float4*>(&buf[CIDX(16*t)]);
            #pragma unroll
            for (int j2 = 0; j2 < 8; ++j2) {
                float4 zv = lp[j2];
                z[2*j2]   = make_float2(zv.x, zv.y);
                z[2*j2+1] = make_float2(zv.z, zv.w);
            }
            cf A[4][4];
            #pragma unroll
            for (int bb = 0; bb < 4; ++bb) {
                cf a0 = z[bb], a1 = z[bb+4], a2 = z[bb+8], a3 = z[bb+12];
                cf s0 = cadd(a0,a2), d0 = csub(a0,a2);
                cf s1 = cadd(a1,a3), d1 = csub(a1,a3);
                A[bb][0] = cadd(s0,s1);
                A[bb][1] = make_float2(d0.x + d1.y, d0.y - d1.x);
                A[bb][2] = csub(s0,s1);
                A[bb][3] = make_float2(d0.x - d1.y, d0.y + d1.x);
            }
            cf F0 = cadd(cadd(A[0][0], A[1][0]),      cadd(A[2][0],      A[3][0]));
            cf F1 = cadd(cadd(A[0][1], cW1(A[1][1])), cadd(cW2(A[2][1]), cW3(A[3][1])));
            cf F2 = cadd(cadd(A[0][2], cW2(A[1][2])), cadd(cmulNI(A[2][2]), cW6(A[3][2])));
            cf F3 = cadd(cadd(A[0][3], cW3(A[1][3])), cadd(cW6(A[2][3]), cNW1(A[3][3])));

            cf h, P0, P1, P2, P3;
            h = make_float2(fmaxf(F0.x,0.f), fmaxf(F0.y,0.f)); P0 = cmul(h, w2v0);
            h = make_float2(fmaxf(F1.x,0.f), fmaxf(F1.y,0.f)); P1 = cmul(h, w2v1);
            h = make_float2(fmaxf(F2.x,0.f), fmaxf(F2.y,0.f)); P2 = cmul(h, w2v2);
            h = make_float2(fmaxf(F3.x,0.f), fmaxf(F3.y,0.f)); P3 = cmul(h, w2v3);

            cf s0 = cadd(P0,P2), d0 = csub(P0,P2);
            cf s1 = cadd(P1,P3), d1 = csub(P1,P3);
            cf G0 = cadd(s0,s1);
            cf G1 = make_float2(d0.x + d1.y, d0.y - d1.x);
            cf G2 = csub(s0,s1);
            cf G3 = make_float2(d0.x - d1.y, d0.y + d1.x);
            acc0 = G0;
            acc1 = cmul(G1, r1);
            acc2 = cmul(G2, r2);
            acc3 = cmul(G3, r3);
            acc4 = cmul(G0, r4);
        }

        // ---- reduce 256 threads -> 10 floats, store row ----
        float rv[10] = {acc0.x, acc0.y, acc1.x, acc1.y, acc2.x,
                        acc2.y, acc3.x, acc3.y, acc4.x, acc4.y};
        #pragma unroll
        for (int i = 0; i < 10; ++i) rv[i] = wred(rv[i]);
        const int lane = t & 63, wv = t >> 6;
        if (lane == 63) {
            #pragma unroll
            for (int i = 0; i < 10; ++i) sred[wv*10 + i] = rv[i];
        }
        bar_lds();   // sred visible; also: all final buf-reads done -> next pass A may write
        if (t < 10) {
            out[(b0 + rr)*10 + t] = sred[t] + sred[10+t] + sred[20+t] + sred[30+t];
        }
    }
}

extern "C" void kernel_launch(void* const* d_in, const int* in_sizes, int n_in,
                              void* d_out, int out_size, void* d_ws, size_t ws_size,
                              hipStream_t stream) {
    const float* x  = (const float*)d_in[0];
    const float* w1 = (const float*)d_in[1];
    const float* w2 = (const float*)d_in[2];
    float* out = (float*)d_out;
    fftmlp_r16ip<<<NBLK, 256, 0, stream>>>(x, w1, w2, out);
}

// Round 7
// 96.625 us; speedup vs baseline: 4.3016x; 4.0560x over previous
//
#include <hip/hip_runtime.h>

#define NBLK 8192
#define R2F 0.70710678118654752f
#define TWO_PI 6.28318530717958648f

// +2 complex every 32: breaks pow2 strides, preserves 16B alignment
#define CIDX(c) ((c) + (((c) >> 5) << 1))

typedef float2 cf;

__device__ __forceinline__ cf cadd(cf a, cf b){ return make_float2(a.x+b.x, a.y+b.y); }
__device__ __forceinline__ cf csub(cf a, cf b){ return make_float2(a.x-b.x, a.y-b.y); }
__device__ __forceinline__ cf cmul(cf a, cf b){ return make_float2(a.x*b.x - a.y*b.y, a.x*b.y + a.y*b.x); }
__device__ __forceinline__ cf cmulNI(cf a){ return make_float2(a.y, -a.x); }                 // * (-i)
__device__ __forceinline__ cf cW8(cf a){ return make_float2(R2F*(a.x + a.y), R2F*(a.y - a.x)); }   // * W8^1
__device__ __forceinline__ cf cW83(cf a){ return make_float2(R2F*(a.y - a.x), -R2F*(a.x + a.y)); } // * W8^3

// in-register 8-point DFT, natural in / natural out (v[p] = bin p)
__device__ __forceinline__ void fft8(cf v[8]) {
    cf s0=cadd(v[0],v[4]), s1=cadd(v[1],v[5]), s2=cadd(v[2],v[6]), s3=cadd(v[3],v[7]);
    cf d0=csub(v[0],v[4]), d1=csub(v[1],v[5]), d2=csub(v[2],v[6]), d3=csub(v[3],v[7]);
    cf t1=cW8(d1), t2=cmulNI(d2), t3=cW83(d3);
    cf ss0=cadd(s0,s2), ss1=cadd(s1,s3), sd0=csub(s0,s2), sd1=csub(s1,s3);
    v[0]=cadd(ss0,ss1);
    v[2]=make_float2(sd0.x+sd1.y, sd0.y-sd1.x);
    v[4]=csub(ss0,ss1);
    v[6]=make_float2(sd0.x-sd1.y, sd0.y+sd1.x);
    cf tt0=cadd(d0,t2), tt1=cadd(t1,t3), td0=csub(d0,t2), td1=csub(t1,t3);
    v[1]=cadd(tt0,tt1);
    v[3]=make_float2(td0.x+td1.y, td0.y-td1.x);
    v[5]=csub(tt0,tt1);
    v[7]=make_float2(td0.x-td1.y, td0.y+td1.x);
}

// 64-lane sum via DPP; valid in lane 63
__device__ __forceinline__ float wred(float x) {
    x += __int_as_float(__builtin_amdgcn_update_dpp(0, __float_as_int(x), 0x111, 0xf, 0xf, false));
    x += __int_as_float(__builtin_amdgcn_update_dpp(0, __float_as_int(x), 0x112, 0xf, 0xf, false));
    x += __int_as_float(__builtin_amdgcn_update_dpp(0, __float_as_int(x), 0x114, 0xf, 0xf, false));
    x += __int_as_float(__builtin_amdgcn_update_dpp(0, __float_as_int(x), 0x118, 0xf, 0xf, false));
    x += __int_as_float(__builtin_amdgcn_update_dpp(0, __float_as_int(x), 0x142, 0xa, 0xf, false));
    x += __int_as_float(__builtin_amdgcn_update_dpp(0, __float_as_int(x), 0x143, 0xc, 0xf, false));
    return x;
}

__global__ __launch_bounds__(512, 8)
void fftmlp_r8(const float* __restrict__ x, const float* __restrict__ w1,
               const float* __restrict__ w2, float* __restrict__ out) {
    __shared__ __align__(16) cf buf[CIDX(4095) + 1];
    __shared__ float sred[80];
    const int t = threadIdx.x;
    const int b = blockIdx.x;
    const cf* __restrict__ xr  = (const cf*)x + (size_t)b * 4096;
    const cf* __restrict__ w1c = (const cf*)w1;
    const cf* __restrict__ w2c = (const cf*)w2;
    float sn, cs;

    // ---- pass 0: global load x*w1, fft8 over stride 512, twiddle W_4096^t ----
    {
        cf v[8];
        #pragma unroll
        for (int k = 0; k < 8; ++k)
            v[k] = cmul(xr[t + 512*k], w1c[t + 512*k]);
        fft8(v);
        __sincosf(-TWO_PI * (float)t * (1.0f/4096.0f), &sn, &cs);
        cf w = make_float2(cs, sn);
        buf[CIDX(t)] = v[0];
        cf tw = w;
        #pragma unroll
        for (int p = 1; p < 8; ++p) {
            buf[CIDX(t + 512*p)] = cmul(v[p], tw);
            tw = cmul(tw, w);
        }
    }
    __syncthreads();

    // ---- pass 1: within 512-blocks, stride 64, twiddle W_512^(t&63) ----
    {
        const int base = ((t >> 6) << 9) | (t & 63);
        cf v[8];
        #pragma unroll
        for (int k = 0; k < 8; ++k) v[k] = buf[CIDX(base + 64*k)];
        fft8(v);
        __sincosf(-TWO_PI * (float)(t & 63) * (1.0f/512.0f), &sn, &cs);
        cf w = make_float2(cs, sn);
        buf[CIDX(base)] = v[0];
        cf tw = w;
        #pragma unroll
        for (int p = 1; p < 8; ++p) {
            buf[CIDX(base + 64*p)] = cmul(v[p], tw);
            tw = cmul(tw, w);
        }
    }
    __syncthreads();

    // ---- pass 2: within 64-blocks, stride 8, twiddle W_64^(t&7) ----
    {
        const int base = ((t >> 3) << 6) | (t & 7);
        cf v[8];
        #pragma unroll
        for (int k = 0; k < 8; ++k) v[k] = buf[CIDX(base + 8*k)];
        fft8(v);
        __sincosf(-TWO_PI * (float)(t & 7) * (1.0f/64.0f), &sn, &cs);
        cf w = make_float2(cs, sn);
        buf[CIDX(base)] = v[0];
        cf tw = w;
        #pragma unroll
        for (int p = 1; p < 8; ++p) {
            buf[CIDX(base + 8*p)] = cmul(v[p], tw);
            tw = cmul(tw, w);
        }
    }
    __syncthreads();

    // ---- final: contiguous 8-group; only bins n0 (p=0) and n0+512 (p=1) needed ----
    float rv[10];
    {
        cf z[8];
        const float4* __restrict__ lp = reinterpret_cast<const float4*>(&buf[CIDX(8*t)]);
        #pragma unroll
        for (int j2 = 0; j2 < 4; ++j2) {
            float4 q = lp[j2];
            z[2*j2]   = make_float2(q.x, q.y);
            z[2*j2+1] = make_float2(q.z, q.w);
        }
        cf F0 = cadd(cadd(cadd(z[0],z[1]), cadd(z[2],z[3])),
                     cadd(cadd(z[4],z[5]), cadd(z[6],z[7])));
        cf d0=csub(z[0],z[4]), d1=csub(z[1],z[5]), d2=csub(z[2],z[6]), d3=csub(z[3],z[7]);
        cf F1 = cadd(cadd(d0, cW8(d1)), cadd(cmulNI(d2), cW83(d3)));

        // bin n0 = octal-reverse of t (3 digits)
        const int n0 = ((t & 7) << 6) | (t & 56) | ((t >> 6) & 7);
        cf h0 = make_float2(fmaxf(F0.x, 0.f), fmaxf(F0.y, 0.f));
        cf h1 = make_float2(fmaxf(F1.x, 0.f), fmaxf(F1.y, 0.f));
        cf P0 = cmul(h0, w2c[n0]);
        cf P1 = cmul(h1, w2c[512 + n0]);
        // bin n0+512 contributes with W_1024^{512k} = (-1)^k
        cf E = cadd(P0, P1), O = csub(P0, P1);
        __sincosf(-TWO_PI * (float)n0 * (1.0f/1024.0f), &sn, &cs);
        cf W1v = make_float2(cs, sn);
        cf W2v = cmul(W1v, W1v);
        cf W3v = cmul(W2v, W1v);
        cf W4v = cmul(W2v, W2v);
        cf a1 = cmul(O, W1v);
        cf a2 = cmul(E, W2v);
        cf a3 = cmul(O, W3v);
        cf a4 = cmul(E, W4v);
        rv[0]=E.x;  rv[1]=E.y;  rv[2]=a1.x; rv[3]=a1.y; rv[4]=a2.x;
        rv[5]=a2.y; rv[6]=a3.x; rv[7]=a3.y; rv[8]=a4.x; rv[9]=a4.y;
    }

    // ---- reduce 512 threads (8 waves) -> 10 floats ----
    #pragma unroll
    for (int i = 0; i < 10; ++i) rv[i] = wred(rv[i]);
    const int lane = t & 63, wv = t >> 6;
    if (lane == 63) {
        #pragma unroll
        for (int i = 0; i < 10; ++i) sred[wv*10 + i] = rv[i];
    }
    __syncthreads();
    if (t < 10) {
        float s = sred[t];
        #pragma unroll
        for (int w = 1; w < 8; ++w) s += sred[w*10 + t];
        out[b*10 + t] = s;
    }
}

extern "C" void kernel_launch(void* const* d_in, const int* in_sizes, int n_in,
                              void* d_out, int out_size, void* d_ws, size_t ws_size,
                              hipStream_t stream) {
    const float* x  = (const float*)d_in[0];
    const float* w1 = (const float*)d_in[1];
    const float* w2 = (const float*)d_in[2];
    float* out = (float*)d_out;
    fftmlp_r8<<<NBLK, 512, 0, stream>>>(x, w1, w2, out);
}